// Round 1
// baseline (4848.381 us; speedup 1.0000x reference)
//
#include <hip/hip_runtime.h>
#include <math.h>

#define NN 4096
#define HD 128
#define TT 64

// ---------------- Erel precompute: Erel[r][o], r = rel+63, rel = t-s ----------------
__global__ void erel_kernel(const float* __restrict__ t_w,
                            const float* __restrict__ t_b,
                            float* __restrict__ Erel) {
  int r = blockIdx.x;       // 0..127 (row 127 is padding, never consumed)
  int o = threadIdx.x;      // 0..127
  __shared__ float sc[128];
  float rel = (float)(r - 63);
  if (o < 64) {
    float f = expf((float)o * (-logf(10000.0f) / 63.0f));
    float a = rel * f;
    sc[o] = sinf(a);
    sc[o + 64] = cosf(a);
  }
  __syncthreads();
  float acc = t_b[o];
  for (int i = 0; i < 128; ++i) acc = fmaf(sc[i], t_w[i * 128 + o], acc);
  Erel[r * 128 + o] = acc;
}

// outT[o0+j][t] = act( b[o0+j] + sum_h inT[h][t] * W[h*128+o0+j] )
template <bool SILU>
__device__ __forceinline__ void mlp_layer(const float (*inT)[68], float (*outT)[68],
                                          const float* __restrict__ W,
                                          const float* __restrict__ b,
                                          int t, int o0) {
  float acc[32];
#pragma unroll
  for (int j = 0; j < 32; ++j) acc[j] = b[o0 + j];
  for (int h = 0; h < 128; ++h) {
    float xv = inT[h][t];
#pragma unroll
    for (int j = 0; j < 32; ++j) acc[j] = fmaf(xv, W[h * 128 + o0 + j], acc[j]);
  }
#pragma unroll
  for (int j = 0; j < 32; ++j) {
    float r = acc[j];
    if (SILU) r = r * (1.0f / (1.0f + __expf(-r)));
    outT[o0 + j][t] = r;
  }
}

__launch_bounds__(256)
__global__ void et_layer_kernel(const float* __restrict__ xg,
                                const float* __restrict__ hg,
                                const float* __restrict__ qw1, const float* __restrict__ qb1,
                                const float* __restrict__ qw2, const float* __restrict__ qb2,
                                const float* __restrict__ kw1, const float* __restrict__ kb1,
                                const float* __restrict__ kw2, const float* __restrict__ kb2,
                                const float* __restrict__ vw1, const float* __restrict__ vb1,
                                const float* __restrict__ vw2, const float* __restrict__ vb2,
                                const float* __restrict__ xmw1, const float* __restrict__ xmb1,
                                const float* __restrict__ xmw2, const float* __restrict__ xmb2,
                                const float* __restrict__ Erel,
                                float* __restrict__ xout, float* __restrict__ hout) {
  // T-major LDS buffers [channel][token], stride 68 (conflict-free along t, 16B-aligned rows)
  __shared__ float tokT[128][68];   // tok; later v
  __shared__ float hidT[128][68];   // hidden; later QE2[r][t]; later A2T[r][t]
  __shared__ float qT[128][68];
  __shared__ float kT[128][68];
  __shared__ float sco[64][68];     // scores/alpha [t][s]
  __shared__ float vx[64];
  __shared__ float xls[3][64];

  const int tid = threadIdx.x;
  const int t = tid & 63;
  const int wv = tid >> 6;
  const int n = blockIdx.x;
  const int o0 = __builtin_amdgcn_readfirstlane(wv << 5);   // wave's 32-channel tile

  // ---- load x and h (transposed into tokT) ----
  if (tid < 192) xls[tid >> 6][tid & 63] = xg[n * 192 + tid];
  const float* hrow = hg + (size_t)n * 8192;
#pragma unroll
  for (int j = 0; j < 32; ++j) {
    int hh = o0 + j;
    tokT[hh][t] = hrow[hh * 64 + t];
  }
  __syncthreads();

  // ---- q, k, v, and xm-hidden MLPs ----
  mlp_layer<true >(tokT, hidT, qw1, qb1, t, o0);  __syncthreads();
  mlp_layer<false>(hidT, qT,   qw2, qb2, t, o0);  __syncthreads();
  mlp_layer<true >(tokT, hidT, kw1, kb1, t, o0);  __syncthreads();
  mlp_layer<false>(hidT, kT,   kw2, kb2, t, o0);  __syncthreads();
  mlp_layer<true >(tokT, hidT, vw1, vb1, t, o0);  __syncthreads();
  mlp_layer<false>(hidT, tokT, vw2, vb2, t, o0);  __syncthreads();   // v overlays tokT
  mlp_layer<true >(tokT, hidT, xmw1, xmb1, t, o0); __syncthreads();  // hidX

  // vx[t] = hidX[:,t] . xm_w2 + xm_b2
  if (wv == 0) {
    float a = xmb2[0];
    for (int h = 0; h < 128; ++h) a = fmaf(hidT[h][t], xmw2[h], a);
    vx[t] = a;
  }
  __syncthreads();

  // ---- QE2[r][t] = q[t] . Erel[r]  (into hidT) ----
  {
    float acc[32];
#pragma unroll
    for (int j = 0; j < 32; ++j) acc[j] = 0.f;
    for (int h = 0; h < 128; ++h) {
      float qv = qT[h][t];
#pragma unroll
      for (int j = 0; j < 32; ++j) acc[j] = fmaf(qv, Erel[(o0 + j) * 128 + h], acc[j]);
    }
#pragma unroll
    for (int j = 0; j < 32; ++j) hidT[o0 + j][t] = acc[j];
  }
  __syncthreads();

  // ---- scores[t][s] = q[t].k[s] + QE2[t-s+63][t] ----
  {
    const int s = t;                                            // lanes along s
    const int t0 = __builtin_amdgcn_readfirstlane(wv << 4);     // 16 t's per wave
    float acc[16];
#pragma unroll
    for (int i = 0; i < 16; ++i) acc[i] = 0.f;
    for (int h = 0; h < 128; ++h) {
      float kv = kT[h][s];
#pragma unroll
      for (int ii = 0; ii < 4; ++ii) {
        float4 q4 = *(const float4*)&qT[h][t0 + 4 * ii];
        acc[4 * ii + 0] = fmaf(q4.x, kv, acc[4 * ii + 0]);
        acc[4 * ii + 1] = fmaf(q4.y, kv, acc[4 * ii + 1]);
        acc[4 * ii + 2] = fmaf(q4.z, kv, acc[4 * ii + 2]);
        acc[4 * ii + 3] = fmaf(q4.w, kv, acc[4 * ii + 3]);
      }
    }
#pragma unroll
    for (int i = 0; i < 16; ++i) {
      int tt = t0 + i;
      sco[tt][s] = acc[i] + hidT[tt - s + 63][tt];
    }
  }
  __syncthreads();

  // ---- softmax over s (rows handled by wave 0) ----
  if (wv == 0) {
    float m = -1e30f;
    for (int s2 = 0; s2 < 64; ++s2) m = fmaxf(m, sco[t][s2]);
    float sum = 0.f;
    for (int s2 = 0; s2 < 64; ++s2) {
      float e = __expf(sco[t][s2] - m);
      sum += e;
      sco[t][s2] = e;
    }
    float inv = 1.0f / sum;
    for (int s2 = 0; s2 < 64; ++s2) sco[t][s2] *= inv;
  }
  __syncthreads();

  // ---- A2T[r][t] = alpha[t][t+63-r] (band scatter), into hidT ----
#pragma unroll
  for (int j = 0; j < 32; ++j) {
    int r = o0 + j;
    int s2 = t + 63 - r;
    hidT[r][t] = (s2 >= 0 && s2 < 64) ? sco[t][s2] : 0.f;
  }
  __syncthreads();

  // ---- x update ----
  if (tid < 192) {
    int d = tid >> 6;
    float a1 = 0.f, a2 = 0.f;
    for (int s2 = 0; s2 < 64; ++s2) {
      float w = sco[t][s2] * vx[s2];
      a1 += w;
      a2 = fmaf(w, xls[d][s2], a2);
    }
    float xv = xls[d][t];
    xout[n * 192 + tid] = fmaf(xv, a1, xv) - a2;
  }

  // ---- dh[t][hh] = sum_s alpha[t][s] v[s][hh] + sum_r A2[t][r] Erel[r][hh]; h_out = h + dh ----
  {
    float acc[32];
#pragma unroll
    for (int j = 0; j < 32; ++j) acc[j] = 0.f;
    for (int s2 = 0; s2 < 64; ++s2) {
      float a = sco[t][s2];
#pragma unroll
      for (int j = 0; j < 32; ++j) acc[j] = fmaf(a, tokT[o0 + j][s2], acc[j]);  // tokT holds v
    }
    for (int r = 0; r < 127; ++r) {
      float a = hidT[r][t];
#pragma unroll
      for (int j = 0; j < 32; ++j) acc[j] = fmaf(a, Erel[r * 128 + o0 + j], acc[j]);
    }
#pragma unroll
    for (int j = 0; j < 32; ++j) {
      int hh = o0 + j;
      hout[(size_t)n * 8192 + hh * 64 + t] = hrow[hh * 64 + t] + acc[j];
    }
  }
}

extern "C" void kernel_launch(void* const* d_in, const int* in_sizes, int n_in,
                              void* d_out, int out_size, void* d_ws, size_t ws_size,
                              hipStream_t stream) {
  const float* xg   = (const float*)d_in[0];
  const float* hg   = (const float*)d_in[1];
  const float* qw1  = (const float*)d_in[2];
  const float* qb1  = (const float*)d_in[3];
  const float* qw2  = (const float*)d_in[4];
  const float* qb2  = (const float*)d_in[5];
  const float* kw1  = (const float*)d_in[6];
  const float* kb1  = (const float*)d_in[7];
  const float* kw2  = (const float*)d_in[8];
  const float* kb2  = (const float*)d_in[9];
  const float* vw1  = (const float*)d_in[10];
  const float* vb1  = (const float*)d_in[11];
  const float* vw2  = (const float*)d_in[12];
  const float* vb2  = (const float*)d_in[13];
  const float* xmw1 = (const float*)d_in[14];
  const float* xmb1 = (const float*)d_in[15];
  const float* xmw2 = (const float*)d_in[16];
  const float* xmb2 = (const float*)d_in[17];
  const float* t_w  = (const float*)d_in[18];
  const float* t_b  = (const float*)d_in[19];

  float* Erel = (float*)d_ws;                 // 128*128*4 = 64 KB
  float* xout = (float*)d_out;                // [4096,3,64]
  float* hout = xout + (size_t)NN * 3 * TT;   // [4096,128,64]

  erel_kernel<<<128, 128, 0, stream>>>(t_w, t_b, Erel);
  et_layer_kernel<<<NN, 256, 0, stream>>>(xg, hg,
                                          qw1, qb1, qw2, qb2,
                                          kw1, kb1, kw2, kb2,
                                          vw1, vb1, vw2, vb2,
                                          xmw1, xmb1, xmw2, xmb2,
                                          Erel, xout, hout);
}

// Round 2
// 345.940 us; speedup vs baseline: 14.0151x; 14.0151x over previous
//
#include <hip/hip_runtime.h>
#include <math.h>

#define NN 4096

typedef __attribute__((ext_vector_type(8))) short s8v;   // 8 bf16
typedef __attribute__((ext_vector_type(4))) float f4v;   // MFMA accum
typedef unsigned short u16;

static __device__ __forceinline__ f4v MFMA16(s8v a, s8v b, f4v c) {
  return __builtin_amdgcn_mfma_f32_16x16x32_bf16(a, b, c, 0, 0, 0);
}
static __device__ __forceinline__ u16 f2bf(float f) {
  union { float f; unsigned int u; } v; v.f = f;
  unsigned int r = v.u + 0x7fffu + ((v.u >> 16) & 1u);
  return (u16)(r >> 16);
}
static __device__ __forceinline__ float bf2f(u16 u) {
  union { unsigned int u; float f; } v; v.u = ((unsigned int)u) << 16;
  return v.f;
}

// ---------------- weight prep: WT_bf16[o][h] = W[h][o] ----------------
__global__ void wt_prep(const float* __restrict__ qw1, const float* __restrict__ qw2,
                        const float* __restrict__ kw1, const float* __restrict__ kw2,
                        const float* __restrict__ vw1, const float* __restrict__ vw2,
                        const float* __restrict__ xmw1, u16* __restrict__ dst) {
  const float* W;
  switch (blockIdx.x) {
    case 0: W = qw1; break; case 1: W = qw2; break;
    case 2: W = kw1; break; case 3: W = kw2; break;
    case 4: W = vw1; break; case 5: W = vw2; break;
    default: W = xmw1; break;
  }
  u16* o = dst + blockIdx.x * 16384;
  for (int i = 0; i < 64; ++i) {
    int idx = i * 256 + threadIdx.x;
    int h = idx >> 7, c = idx & 127;
    o[c * 128 + h] = f2bf(W[idx]);
  }
}

// ---------------- Erel prep: ErelB[r][h], ErelT[h][r] (bf16) ----------------
__global__ void erel_prep(const float* __restrict__ t_w, const float* __restrict__ t_b,
                          u16* __restrict__ ErelB, u16* __restrict__ ErelT) {
  int r = blockIdx.x;       // 0..127  (rel = r-63)
  int o = threadIdx.x;      // 0..127
  __shared__ float sc[128];
  float rel = (float)(r - 63);
  if (o < 64) {
    float f = expf((float)o * (-logf(10000.0f) / 63.0f));
    float a = rel * f;
    sc[o] = sinf(a);
    sc[o + 64] = cosf(a);
  }
  __syncthreads();
  float acc = t_b[o];
  for (int i = 0; i < 128; ++i) acc = fmaf(sc[i], t_w[i * 128 + o], acc);
  u16 b = f2bf(acc);
  ErelB[r * 128 + o] = b;
  ErelT[o * 128 + r] = b;
}

// generic channel-GEMM: D[m=o][n=t] = A(global,[o][k],stride128) x B(LDS,[t][k],stride136)
template <bool SILU, bool HASB, bool VT>
__device__ __forceinline__ void gemm128(const u16* __restrict__ Ag,
                                        const u16* __restrict__ Bl,
                                        u16* __restrict__ Ol,
                                        u16* __restrict__ vTout,
                                        const float* __restrict__ bias,
                                        int w, int l) {
  const int lr = l & 15, lk = l >> 4;
  const int m0 = w * 16;
  f4v acc[4];
  float bj[4];
#pragma unroll
  for (int j = 0; j < 4; ++j) bj[j] = HASB ? bias[m0 + lk * 4 + j] : 0.f;
#pragma unroll
  for (int ni = 0; ni < 4; ++ni)
#pragma unroll
    for (int j = 0; j < 4; ++j) acc[ni][j] = bj[j];
#pragma unroll
  for (int kt = 0; kt < 4; ++kt) {
    s8v a = *(const s8v*)&Ag[(m0 + lr) * 128 + kt * 32 + lk * 8];
#pragma unroll
    for (int ni = 0; ni < 4; ++ni) {
      s8v b = *(const s8v*)&Bl[(ni * 16 + lr) * 136 + kt * 32 + lk * 8];
      acc[ni] = MFMA16(a, b, acc[ni]);
    }
  }
#pragma unroll
  for (int ni = 0; ni < 4; ++ni) {
    int t = ni * 16 + lr;
    u16 pk[4];
#pragma unroll
    for (int j = 0; j < 4; ++j) {
      float v = acc[ni][j];
      if (SILU) v = v * (1.0f / (1.0f + __expf(-v)));
      pk[j] = f2bf(v);
    }
    *(ushort4*)&Ol[t * 136 + m0 + lk * 4] = make_ushort4(pk[0], pk[1], pk[2], pk[3]);
    if (VT) {
#pragma unroll
      for (int j = 0; j < 4; ++j) vTout[(m0 + lk * 4 + j) * 72 + t] = pk[j];
    }
  }
}

#define OFF_TOK 0
#define OFF_HID 18432
#define OFF_Q   35840
#define OFF_K   53248
#define OFF_V   70656
#define OFF_VX  88064
#define OFF_XLS 88320
#define OFF_VXW 89088
#define SMEM_SZ 89600

__launch_bounds__(512)
__global__ void et_main(const float* __restrict__ xg, const float* __restrict__ hg,
                        const u16* __restrict__ wsb,
                        const float* __restrict__ qb1, const float* __restrict__ qb2,
                        const float* __restrict__ kb1, const float* __restrict__ kb2,
                        const float* __restrict__ vb1, const float* __restrict__ vb2,
                        const float* __restrict__ xmb1, const float* __restrict__ xmw2,
                        const float* __restrict__ xmb2,
                        float* __restrict__ xout, float* __restrict__ hout) {
  __shared__ __align__(16) unsigned char smem[SMEM_SZ];
  u16* tok   = (u16*)(smem + OFF_TOK);
  u16* vT    = (u16*)(smem + OFF_TOK);
  u16* hid   = (u16*)(smem + OFF_HID);
  float* scoF = (float*)(smem + OFF_HID);
  u16* qb    = (u16*)(smem + OFF_Q);
  u16* A2b   = (u16*)(smem + OFF_Q);
  u16* kbuf  = (u16*)(smem + OFF_K);
  u16* alpB  = (u16*)(smem + OFF_K);
  u16* vbuf  = (u16*)(smem + OFF_V);
  u16* qE    = (u16*)(smem + OFF_V);
  float* vxb = (float*)(smem + OFF_VX);
  float* xls = (float*)(smem + OFF_XLS);
  float* vxw = (float*)(smem + OFF_VXW);

  const u16* WTq1 = wsb + 0 * 16384;
  const u16* WTq2 = wsb + 1 * 16384;
  const u16* WTk1 = wsb + 2 * 16384;
  const u16* WTk2 = wsb + 3 * 16384;
  const u16* WTv1 = wsb + 4 * 16384;
  const u16* WTv2 = wsb + 5 * 16384;
  const u16* WTxm = wsb + 6 * 16384;
  const u16* ErelB = wsb + 7 * 16384;
  const u16* ErelT = wsb + 8 * 16384;

  const int tid = threadIdx.x;
  const int l = tid & 63;
  const int w = __builtin_amdgcn_readfirstlane(tid >> 6);
  const int n = blockIdx.x;
  const size_t hbase = (size_t)n * 8192;

  // ---- load x, xm_w2, transposed tok ----
  if (tid < 192) xls[tid] = xg[n * 192 + tid];
  else if (tid < 320) vxw[tid - 192] = xmw2[tid - 192];
  {
    int t = tid & 63, hp = tid >> 6;
#pragma unroll
    for (int it = 0; it < 8; ++it) {
      int hh = it * 16 + hp * 2;
      float a0 = hg[hbase + (size_t)hh * 64 + t];
      float a1 = hg[hbase + (size_t)(hh + 1) * 64 + t];
      unsigned int pk = (unsigned int)f2bf(a0) | ((unsigned int)f2bf(a1) << 16);
      *(unsigned int*)&tok[t * 136 + hh] = pk;
    }
  }
  __syncthreads();

  gemm128<true , true, false>(WTq1, tok, hid, nullptr, qb1, w, l); __syncthreads();
  gemm128<false, true, false>(WTq2, hid, qb , nullptr, qb2, w, l); __syncthreads();
  gemm128<true , true, false>(WTk1, tok, hid, nullptr, kb1, w, l); __syncthreads();
  gemm128<false, true, false>(WTk2, hid, kbuf, nullptr, kb2, w, l); __syncthreads();
  gemm128<true , true, false>(WTv1, tok, hid, nullptr, vb1, w, l); __syncthreads();
  gemm128<false, true, true >(WTv2, hid, vbuf, vT    , vb2, w, l); __syncthreads();
  gemm128<true , true, false>(WTxm, vbuf, hid, nullptr, xmb1, w, l); __syncthreads();

  // ---- vx reduce + qE GEMM ----
  {
    int t = tid >> 3, g = tid & 7;
    float sum = 0.f;
#pragma unroll
    for (int c = 0; c < 16; ++c) sum += bf2f(hid[t * 136 + g * 16 + c]) * vxw[g * 16 + c];
    sum += __shfl_xor(sum, 1, 64);
    sum += __shfl_xor(sum, 2, 64);
    sum += __shfl_xor(sum, 4, 64);
    if (g == 0) vxb[t] = sum + xmb2[0];
  }
  gemm128<false, false, false>(ErelB, qb, qE, nullptr, nullptr, w, l);
  __syncthreads();

  // ---- scores ----
  {
    const int lr = l & 15, lk = l >> 4;
    const int m0 = (w & 3) * 16;
    const int n0 = (w >> 2) * 32;
    f4v acc[2];
#pragma unroll
    for (int ni = 0; ni < 2; ++ni)
#pragma unroll
      for (int j = 0; j < 4; ++j) acc[ni][j] = 0.f;
#pragma unroll
    for (int kt = 0; kt < 4; ++kt) {
      s8v a = *(const s8v*)&kbuf[(m0 + lr) * 136 + kt * 32 + lk * 8];
#pragma unroll
      for (int ni = 0; ni < 2; ++ni) {
        s8v b = *(const s8v*)&qb[(n0 + ni * 16 + lr) * 136 + kt * 32 + lk * 8];
        acc[ni] = MFMA16(a, b, acc[ni]);
      }
    }
#pragma unroll
    for (int ni = 0; ni < 2; ++ni) {
      int t = n0 + ni * 16 + lr;
      float4 out;
      float* op = (float*)&out;
#pragma unroll
      for (int j = 0; j < 4; ++j) {
        int s = m0 + lk * 4 + j;
        int r = t + 63 - s;
        op[j] = acc[ni][j] + bf2f(qE[t * 136 + r]);
      }
      *(float4*)&scoF[t * 68 + m0 + lk * 4] = out;
    }
  }
  __syncthreads();

  // ---- softmax ----
  {
    int t = tid >> 3, g = tid & 7;
    float* row = scoF + t * 68;
    float4 v0 = *(float4*)&row[g * 8];
    float4 v1 = *(float4*)&row[g * 8 + 4];
    float e[8] = {v0.x, v0.y, v0.z, v0.w, v1.x, v1.y, v1.z, v1.w};
    float m = e[0];
#pragma unroll
    for (int i = 1; i < 8; ++i) m = fmaxf(m, e[i]);
    m = fmaxf(m, __shfl_xor(m, 1, 64));
    m = fmaxf(m, __shfl_xor(m, 2, 64));
    m = fmaxf(m, __shfl_xor(m, 4, 64));
    float s = 0.f;
#pragma unroll
    for (int i = 0; i < 8; ++i) { e[i] = __expf(e[i] - m); s += e[i]; }
    s += __shfl_xor(s, 1, 64);
    s += __shfl_xor(s, 2, 64);
    s += __shfl_xor(s, 4, 64);
    float inv = 1.0f / s;
    u16 pk[8];
#pragma unroll
    for (int i = 0; i < 8; ++i) { e[i] *= inv; pk[i] = f2bf(e[i]); }
    *(float4*)&row[g * 8]     = make_float4(e[0], e[1], e[2], e[3]);
    *(float4*)&row[g * 8 + 4] = make_float4(e[4], e[5], e[6], e[7]);
    *(ushort4*)&alpB[t * 72 + g * 8]     = make_ushort4(pk[0], pk[1], pk[2], pk[3]);
    *(ushort4*)&alpB[t * 72 + g * 8 + 4] = make_ushort4(pk[4], pk[5], pk[6], pk[7]);
  }
  __syncthreads();

  // ---- A2 band scatter ----
  {
    int t = tid & 63, rc = tid >> 6;
#pragma unroll
    for (int j = 0; j < 16; ++j) {
      int r = rc * 16 + j;
      int s2 = t + 63 - r;
      float a = (s2 >= 0 && s2 < 64) ? scoF[t * 68 + s2] : 0.f;
      A2b[t * 136 + r] = f2bf(a);
    }
  }
  __syncthreads();

  // ---- x update (waves 0-2) ----
  if (tid < 192) {
    int t = tid & 63, d = tid >> 6;
    float a1 = 0.f, a2 = 0.f;
    for (int s2 = 0; s2 < 64; ++s2) {
      float wv = scoF[t * 68 + s2] * vxb[s2];
      a1 += wv;
      a2 = fmaf(wv, xls[d * 64 + s2], a2);
    }
    float xv = xls[d * 64 + t];
    xout[n * 192 + d * 64 + t] = fmaf(xv, a1, xv) - a2;
  }

  // ---- dh GEMMs + h_out ----
  {
    const int lr = l & 15, lk = l >> 4;
    const int m0 = w * 16;
    f4v acc[4];
#pragma unroll
    for (int ni = 0; ni < 4; ++ni)
#pragma unroll
      for (int j = 0; j < 4; ++j) acc[ni][j] = 0.f;
#pragma unroll
    for (int kt = 0; kt < 2; ++kt) {
      s8v a = *(const s8v*)&vT[(m0 + lr) * 72 + kt * 32 + lk * 8];
#pragma unroll
      for (int ni = 0; ni < 4; ++ni) {
        s8v b = *(const s8v*)&alpB[(ni * 16 + lr) * 72 + kt * 32 + lk * 8];
        acc[ni] = MFMA16(a, b, acc[ni]);
      }
    }
#pragma unroll
    for (int kt = 0; kt < 4; ++kt) {
      s8v a = *(const s8v*)&ErelT[(m0 + lr) * 128 + kt * 32 + lk * 8];
#pragma unroll
      for (int ni = 0; ni < 4; ++ni) {
        s8v b = *(const s8v*)&A2b[(ni * 16 + lr) * 136 + kt * 32 + lk * 8];
        acc[ni] = MFMA16(a, b, acc[ni]);
      }
    }
#pragma unroll
    for (int ni = 0; ni < 4; ++ni) {
      int t = ni * 16 + lr;
      size_t base = hbase + (size_t)(m0 + lk * 4) * 64 + t;
#pragma unroll
      for (int j = 0; j < 4; ++j) hout[base + j * 64] = hg[base + j * 64] + acc[ni][j];
    }
  }
}

extern "C" void kernel_launch(void* const* d_in, const int* in_sizes, int n_in,
                              void* d_out, int out_size, void* d_ws, size_t ws_size,
                              hipStream_t stream) {
  const float* xg   = (const float*)d_in[0];
  const float* hg   = (const float*)d_in[1];
  const float* qw1  = (const float*)d_in[2];
  const float* qb1  = (const float*)d_in[3];
  const float* qw2  = (const float*)d_in[4];
  const float* qb2  = (const float*)d_in[5];
  const float* kw1  = (const float*)d_in[6];
  const float* kb1  = (const float*)d_in[7];
  const float* kw2  = (const float*)d_in[8];
  const float* kb2  = (const float*)d_in[9];
  const float* vw1  = (const float*)d_in[10];
  const float* vb1  = (const float*)d_in[11];
  const float* vw2  = (const float*)d_in[12];
  const float* vb2  = (const float*)d_in[13];
  const float* xmw1 = (const float*)d_in[14];
  const float* xmb1 = (const float*)d_in[15];
  const float* xmw2 = (const float*)d_in[16];
  const float* xmb2 = (const float*)d_in[17];
  const float* t_w  = (const float*)d_in[18];
  const float* t_b  = (const float*)d_in[19];

  u16* wsb = (u16*)d_ws;   // 9 * 16384 u16 = 294912 B
  float* xout = (float*)d_out;
  float* hout = xout + (size_t)NN * 192;

  wt_prep<<<7, 256, 0, stream>>>(qw1, qw2, kw1, kw2, vw1, vw2, xmw1, wsb);
  erel_prep<<<128, 128, 0, stream>>>(t_w, t_b, wsb + 7 * 16384, wsb + 8 * 16384);
  et_main<<<NN, 512, 0, stream>>>(xg, hg, wsb,
                                  qb1, qb2, kb1, kb2, vb1, vb2, xmb1, xmw2, xmb2,
                                  xout, hout);
}

// Round 3
// 244.945 us; speedup vs baseline: 19.7938x; 1.4123x over previous
//
#include <hip/hip_runtime.h>
#include <math.h>

#define NN 4096

typedef __attribute__((ext_vector_type(8))) short s8v;   // 8 bf16 = 16B
typedef __attribute__((ext_vector_type(4))) float f4v;   // MFMA accum
typedef unsigned short u16;

static __device__ __forceinline__ f4v MFMA16(s8v a, s8v b, f4v c) {
  return __builtin_amdgcn_mfma_f32_16x16x32_bf16(a, b, c, 0, 0, 0);
}
static __device__ __forceinline__ u16 f2bf(float f) {
  union { float f; unsigned int u; } v; v.f = f;
  unsigned int r = v.u + 0x7fffu + ((v.u >> 16) & 1u);
  return (u16)(r >> 16);
}
static __device__ __forceinline__ float bf2f(u16 u) {
  union { unsigned int u; float f; } v; v.u = ((unsigned int)u) << 16;
  return v.f;
}

// swizzled byte offsets: 256B rows (128 u16 / 64 f32) and 128B rows (64 u16)
#define SW(row, byte)  ((row) * 256 + ((byte) ^ (((row) & 7) << 4)))
#define SWH(row, byte) ((row) * 128 + ((byte) ^ (((row) & 7) << 4)))

// ---------------- prep: 7 weight transposes (bf16) + Erel both layouts ----------------
__global__ void prep_kernel(const float* __restrict__ qw1, const float* __restrict__ qw2,
                            const float* __restrict__ kw1, const float* __restrict__ kw2,
                            const float* __restrict__ vw1, const float* __restrict__ vw2,
                            const float* __restrict__ xmw1,
                            const float* __restrict__ t_w, const float* __restrict__ t_b,
                            u16* __restrict__ wsb) {
  int b = blockIdx.x;
  if (b < 7) {
    const float* W;
    switch (b) {
      case 0: W = qw1; break; case 1: W = qw2; break;
      case 2: W = kw1; break; case 3: W = kw2; break;
      case 4: W = vw1; break; case 5: W = vw2; break;
      default: W = xmw1; break;
    }
    u16* o = wsb + b * 16384;
    for (int i = 0; i < 128; ++i) {
      int idx = i * 128 + threadIdx.x;
      int h = idx >> 7, c = idx & 127;
      o[c * 128 + h] = f2bf(W[idx]);
    }
  } else {
    int r = b - 7;            // 0..127, rel = r-63
    int o = threadIdx.x;      // 0..127
    __shared__ float sc[128];
    float rel = (float)(r - 63);
    if (o < 64) {
      float f = expf((float)o * (-logf(10000.0f) / 63.0f));
      float a = rel * f;
      sc[o] = sinf(a);
      sc[o + 64] = cosf(a);
    }
    __syncthreads();
    float acc = t_b[o];
    for (int i = 0; i < 128; ++i) acc = fmaf(sc[i], t_w[i * 128 + o], acc);
    u16 bb = f2bf(acc);
    wsb[7 * 16384 + r * 128 + o] = bb;   // ErelB[r][h]
    wsb[8 * 16384 + o * 128 + r] = bb;   // ErelT[h][r]
  }
}

// D[m=o][n=t] = A(global [o][k], stride 128) x B(LDS swizzled [t][k]); out -> Ol[t][o] bf16
template <bool SILU, bool HASB, bool VT>
__device__ __forceinline__ void gemm128(const u16* __restrict__ Ag,
                                        const unsigned char* Bl,
                                        unsigned char* Ol,
                                        unsigned char* vTout,
                                        const float* __restrict__ bias,
                                        int w, int l) {
  const int lr = l & 15, lk = l >> 4;
  const int m0 = w * 16;
  float bj[4];
#pragma unroll
  for (int j = 0; j < 4; ++j) bj[j] = HASB ? bias[m0 + lk * 4 + j] : 0.f;
  f4v acc[4];
#pragma unroll
  for (int ni = 0; ni < 4; ++ni)
#pragma unroll
    for (int j = 0; j < 4; ++j) acc[ni][j] = bj[j];
#pragma unroll
  for (int kt = 0; kt < 4; ++kt) {
    s8v a = *(const s8v*)&Ag[(m0 + lr) * 128 + kt * 32 + lk * 8];
#pragma unroll
    for (int ni = 0; ni < 4; ++ni) {
      s8v b = *(const s8v*)(Bl + SW(ni * 16 + lr, kt * 64 + lk * 16));
      acc[ni] = MFMA16(a, b, acc[ni]);
    }
  }
#pragma unroll
  for (int ni = 0; ni < 4; ++ni) {
    int t = ni * 16 + lr;
    u16 pk[4];
#pragma unroll
    for (int j = 0; j < 4; ++j) {
      float v = acc[ni][j];
      if (SILU) v = v * (1.0f / (1.0f + __expf(-v)));
      pk[j] = f2bf(v);
    }
    *(ushort4*)(Ol + SW(t, m0 * 2 + lk * 8)) = make_ushort4(pk[0], pk[1], pk[2], pk[3]);
    if (VT) {
#pragma unroll
      for (int j = 0; j < 4; ++j)
        *(u16*)(vTout + SWH(m0 + lk * 4 + j, t * 2)) = pk[j];
    }
  }
}

// LDS layout (bytes); total 81920 -> 2 blocks/CU
#define OFF_TOK 0        // tok [64]x256B  -> vT [128]x128B
#define OFF_HID 16384    // hid [64]x256B  -> scoF f32 [64]x256B
#define OFF_Q   32768    // q   [64]x256B  -> A2 [64]x256B
#define OFF_K   49152    // k   [64]x256B  -> alpB [64]x128B (8K) + vx(256B) + xls(768B)
#define OFF_VX  57344
#define OFF_XLS 57600
#define OFF_V   65536    // v   [64]x256B  -> qE [64]x256B
#define SMEM_SZ 81920

__launch_bounds__(512)
__global__ void et_main(const float* __restrict__ xg, const float* __restrict__ hg,
                        const u16* __restrict__ wsb,
                        const float* __restrict__ qb1, const float* __restrict__ qb2,
                        const float* __restrict__ kb1, const float* __restrict__ kb2,
                        const float* __restrict__ vb1, const float* __restrict__ vb2,
                        const float* __restrict__ xmb1, const float* __restrict__ xmw2,
                        const float* __restrict__ xmb2,
                        float* __restrict__ xout, float* __restrict__ hout) {
  __shared__ __align__(16) unsigned char smem[SMEM_SZ];
  unsigned char* TOK = smem + OFF_TOK;
  unsigned char* HID = smem + OFF_HID;
  unsigned char* QB  = smem + OFF_Q;
  unsigned char* KB  = smem + OFF_K;
  unsigned char* VB  = smem + OFF_V;
  unsigned char* VT  = TOK;
  unsigned char* SCO = HID;
  unsigned char* A2  = QB;
  unsigned char* ALP = KB;
  float* vxb = (float*)(smem + OFF_VX);
  float* xls = (float*)(smem + OFF_XLS);

  const u16* WTq1 = wsb + 0 * 16384;
  const u16* WTq2 = wsb + 1 * 16384;
  const u16* WTk1 = wsb + 2 * 16384;
  const u16* WTk2 = wsb + 3 * 16384;
  const u16* WTv1 = wsb + 4 * 16384;
  const u16* WTv2 = wsb + 5 * 16384;
  const u16* WTxm = wsb + 6 * 16384;
  const u16* ErelB = wsb + 7 * 16384;
  const u16* ErelT = wsb + 8 * 16384;

  const int tid = threadIdx.x;
  const int l = tid & 63;
  const int w = __builtin_amdgcn_readfirstlane(tid >> 6);
  const int n = blockIdx.x;
  const size_t hbase = (size_t)n * 8192;

  // ---- tok load: 16B-chunk LDS writes (2 chunks/thread) ----
  {
    int t = tid & 63;
    int c0 = (tid >> 6) * 2;
#pragma unroll
    for (int cc = 0; cc < 2; ++cc) {
      int c = c0 + cc;
      s8v pk;
#pragma unroll
      for (int j = 0; j < 8; ++j)
        pk[j] = (short)f2bf(hg[hbase + (size_t)(c * 8 + j) * 64 + t]);
      *(s8v*)(TOK + SW(t, c * 16)) = pk;
    }
  }
  __syncthreads();

  // ---- MLPs ----
  gemm128<true , true, false>(WTq1, TOK, HID, nullptr, qb1, w, l); __syncthreads();
  gemm128<false, true, false>(WTq2, HID, QB , nullptr, qb2, w, l); __syncthreads();
  gemm128<true , true, false>(WTk1, TOK, HID, nullptr, kb1, w, l); __syncthreads();
  gemm128<false, true, false>(WTk2, HID, KB , nullptr, kb2, w, l); __syncthreads();
  gemm128<true , true, false>(WTv1, TOK, HID, nullptr, vb1, w, l); __syncthreads();
  gemm128<false, true, true >(WTv2, HID, VB , VT     , vb2, w, l); __syncthreads();
  gemm128<true , true, false>(WTxm, VB , HID, nullptr, xmb1, w, l); __syncthreads();

  // ---- vx partial (register) + qE GEMM ----
  float vxreg;
  {
    int t = tid >> 3, g = tid & 7;
    s8v h0 = *(const s8v*)(HID + SW(t, g * 32));
    s8v h1 = *(const s8v*)(HID + SW(t, g * 32 + 16));
    float sum = 0.f;
#pragma unroll
    for (int c = 0; c < 8; ++c) sum = fmaf(bf2f((u16)h0[c]), xmw2[g * 16 + c], sum);
#pragma unroll
    for (int c = 0; c < 8; ++c) sum = fmaf(bf2f((u16)h1[c]), xmw2[g * 16 + 8 + c], sum);
    sum += __shfl_xor(sum, 1, 64);
    sum += __shfl_xor(sum, 2, 64);
    sum += __shfl_xor(sum, 4, 64);
    vxreg = sum;
  }
  gemm128<false, false, false>(ErelB, QB, VB, nullptr, nullptr, w, l);   // qE[t][r]
  __syncthreads();

  // ---- scores[t][s] = q.k + qE[t][t-s+63] -> scoF (over hid) ----
  {
    const int lr = l & 15, lk = l >> 4;
    const int m0 = (w & 3) * 16;     // s tile
    const int n0 = (w >> 2) * 32;    // t tiles
    f4v acc[2];
#pragma unroll
    for (int ni = 0; ni < 2; ++ni)
#pragma unroll
      for (int j = 0; j < 4; ++j) acc[ni][j] = 0.f;
#pragma unroll
    for (int kt = 0; kt < 4; ++kt) {
      s8v a = *(const s8v*)(KB + SW(m0 + lr, kt * 64 + lk * 16));
#pragma unroll
      for (int ni = 0; ni < 2; ++ni) {
        s8v b = *(const s8v*)(QB + SW(n0 + ni * 16 + lr, kt * 64 + lk * 16));
        acc[ni] = MFMA16(a, b, acc[ni]);
      }
    }
#pragma unroll
    for (int ni = 0; ni < 2; ++ni) {
      int t = n0 + ni * 16 + lr;
      float4 out;
      float* op = (float*)&out;
#pragma unroll
      for (int j = 0; j < 4; ++j) {
        int s = m0 + lk * 4 + j;
        int r = t - s + 63;
        op[j] = acc[ni][j] + bf2f(*(const u16*)(VB + SW(t, r * 2)));
      }
      *(float4*)(SCO + SW(t, m0 * 4 + lk * 16)) = out;
    }
  }
  __syncthreads();

  // ---- vx store + x load + softmax (k-buffer now dead) ----
  if ((tid & 7) == 0) vxb[tid >> 3] = vxreg + xmb2[0];
  if (tid < 192) xls[tid] = xg[n * 192 + tid];
  {
    int t = tid >> 3, g = tid & 7;
    float4 v0 = *(float4*)(SCO + SW(t, g * 32));
    float4 v1 = *(float4*)(SCO + SW(t, g * 32 + 16));
    float e[8] = {v0.x, v0.y, v0.z, v0.w, v1.x, v1.y, v1.z, v1.w};
    float m = e[0];
#pragma unroll
    for (int i = 1; i < 8; ++i) m = fmaxf(m, e[i]);
    m = fmaxf(m, __shfl_xor(m, 1, 64));
    m = fmaxf(m, __shfl_xor(m, 2, 64));
    m = fmaxf(m, __shfl_xor(m, 4, 64));
    float s = 0.f;
#pragma unroll
    for (int i = 0; i < 8; ++i) { e[i] = __expf(e[i] - m); s += e[i]; }
    s += __shfl_xor(s, 1, 64);
    s += __shfl_xor(s, 2, 64);
    s += __shfl_xor(s, 4, 64);
    float inv = 1.0f / s;
    s8v pk;
#pragma unroll
    for (int i = 0; i < 8; ++i) { e[i] *= inv; pk[i] = (short)f2bf(e[i]); }
    *(float4*)(SCO + SW(t, g * 32))      = make_float4(e[0], e[1], e[2], e[3]);
    *(float4*)(SCO + SW(t, g * 32 + 16)) = make_float4(e[4], e[5], e[6], e[7]);
    *(s8v*)(ALP + SWH(t, g * 16)) = pk;
  }
  __syncthreads();

  // ---- A2[t][r] = alpha[t][t+63-r] band scatter (from alpB, 16B chunks) ----
  {
    int t = tid >> 3, g = tid & 7;
#pragma unroll
    for (int cc = 0; cc < 2; ++cc) {
      int c = g * 2 + cc;
      s8v pk;
#pragma unroll
      for (int i = 0; i < 8; ++i) {
        int r = c * 8 + i;
        int s2 = t + 63 - r;
        pk[i] = (s2 >= 0 && s2 < 64) ? *(const short*)(ALP + SWH(t, s2 * 2)) : (short)0;
      }
      *(s8v*)(A2 + SW(t, c * 16)) = pk;
    }
  }

  // ---- x update (waves 0-2), rotated inner loop ----
  if (tid < 192) {
    int t = tid & 63, d = tid >> 6;
    float a1 = 0.f, a2 = 0.f;
    for (int i = 0; i < 64; ++i) {
      int s2 = (i + t) & 63;
      float al = *(const float*)(SCO + SW(t, s2 * 4));
      float wv = al * vxb[s2];
      a1 += wv;
      a2 = fmaf(wv, xls[d * 64 + s2], a2);
    }
    float xv = xls[d * 64 + t];
    xout[n * 192 + d * 64 + t] = fmaf(xv, a1, xv) - a2;
  }
  __syncthreads();

  // ---- dh = alpha@v + A2@Erel ; h_out = h + dh ----
  {
    const int lr = l & 15, lk = l >> 4;
    const int m0 = w * 16;
    f4v acc[4];
#pragma unroll
    for (int ni = 0; ni < 4; ++ni)
#pragma unroll
      for (int j = 0; j < 4; ++j) acc[ni][j] = 0.f;
#pragma unroll
    for (int kt = 0; kt < 2; ++kt) {
      s8v a = *(const s8v*)(VT + SWH(m0 + lr, kt * 64 + lk * 16));
#pragma unroll
      for (int ni = 0; ni < 4; ++ni) {
        s8v b = *(const s8v*)(ALP + SWH(ni * 16 + lr, kt * 64 + lk * 16));
        acc[ni] = MFMA16(a, b, acc[ni]);
      }
    }
#pragma unroll
    for (int kt = 0; kt < 4; ++kt) {
      s8v a = *(const s8v*)&ErelT[(m0 + lr) * 128 + kt * 32 + lk * 8];
#pragma unroll
      for (int ni = 0; ni < 4; ++ni) {
        s8v b = *(const s8v*)(A2 + SW(ni * 16 + lr, kt * 64 + lk * 16));
        acc[ni] = MFMA16(a, b, acc[ni]);
      }
    }
#pragma unroll
    for (int ni = 0; ni < 4; ++ni) {
      int t = ni * 16 + lr;
      size_t base = hbase + (size_t)(m0 + lk * 4) * 64 + t;
#pragma unroll
      for (int j = 0; j < 4; ++j) hout[base + j * 64] = hg[base + j * 64] + acc[ni][j];
    }
  }
}

extern "C" void kernel_launch(void* const* d_in, const int* in_sizes, int n_in,
                              void* d_out, int out_size, void* d_ws, size_t ws_size,
                              hipStream_t stream) {
  const float* xg   = (const float*)d_in[0];
  const float* hg   = (const float*)d_in[1];
  const float* qw1  = (const float*)d_in[2];
  const float* qb1  = (const float*)d_in[3];
  const float* qw2  = (const float*)d_in[4];
  const float* qb2  = (const float*)d_in[5];
  const float* kw1  = (const float*)d_in[6];
  const float* kb1  = (const float*)d_in[7];
  const float* kw2  = (const float*)d_in[8];
  const float* kb2  = (const float*)d_in[9];
  const float* vw1  = (const float*)d_in[10];
  const float* vb1  = (const float*)d_in[11];
  const float* vw2  = (const float*)d_in[12];
  const float* vb2  = (const float*)d_in[13];
  const float* xmw1 = (const float*)d_in[14];
  const float* xmb1 = (const float*)d_in[15];
  const float* xmw2 = (const float*)d_in[16];
  const float* xmb2 = (const float*)d_in[17];
  const float* t_w  = (const float*)d_in[18];
  const float* t_b  = (const float*)d_in[19];

  u16* wsb = (u16*)d_ws;   // 9 * 16384 u16 = 294912 B
  float* xout = (float*)d_out;
  float* hout = xout + (size_t)NN * 192;

  prep_kernel<<<135, 128, 0, stream>>>(qw1, qw2, kw1, kw2, vw1, vw2, xmw1, t_w, t_b, wsb);
  et_main<<<NN, 512, 0, stream>>>(xg, hg, wsb,
                                  qb1, qb2, kb1, kb2, vb1, vb2, xmb1, xmw2, xmb2,
                                  xout, hout);
}

// Round 4
// 208.585 us; speedup vs baseline: 23.2442x; 1.1743x over previous
//
#include <hip/hip_runtime.h>
#include <hip/hip_bf16.h>
#include <math.h>

#define NN 4096

typedef __attribute__((ext_vector_type(8))) short s8v;        // 8 bf16 = 16B
typedef __attribute__((ext_vector_type(4))) float f4v;        // MFMA accum
typedef __attribute__((ext_vector_type(4))) unsigned int u32x4;
typedef __attribute__((ext_vector_type(2))) unsigned int u32x2;
typedef unsigned short u16;

static __device__ __forceinline__ f4v MFMA16(s8v a, s8v b, f4v c) {
  return __builtin_amdgcn_mfma_f32_16x16x32_bf16(a, b, c, 0, 0, 0);
}
static __device__ __forceinline__ u16 f2bf(float f) {
  union { float f; unsigned int u; } v; v.f = f;
  unsigned int r = v.u + 0x7fffu + ((v.u >> 16) & 1u);
  return (u16)(r >> 16);
}
static __device__ __forceinline__ float bf2f(u16 u) {
  union { unsigned int u; float f; } v; v.u = ((unsigned int)u) << 16;
  return v.f;
}
// packed RNE f32x2 -> bf16x2 (v_cvt_pk_bf16_f32)
static __device__ __forceinline__ unsigned int cvt2u(float lo, float hi) {
  __hip_bfloat162 h = __float22bfloat162_rn(make_float2(lo, hi));
  union { __hip_bfloat162 b; unsigned int u; } c; c.b = h; return c.u;
}

// swizzled byte offsets: 256B rows and 128B rows
#define SW(row, byte)  ((row) * 256 + ((byte) ^ (((row) & 7) << 4)))
#define SWH(row, byte) ((row) * 128 + ((byte) ^ (((row) & 7) << 4)))

// ---------------- prep: 7 weight transposes (bf16) + Erel both layouts ----------------
__global__ void prep_kernel(const float* __restrict__ qw1, const float* __restrict__ qw2,
                            const float* __restrict__ kw1, const float* __restrict__ kw2,
                            const float* __restrict__ vw1, const float* __restrict__ vw2,
                            const float* __restrict__ xmw1,
                            const float* __restrict__ t_w, const float* __restrict__ t_b,
                            u16* __restrict__ wsb) {
  int b = blockIdx.x;
  if (b < 7) {
    const float* W;
    switch (b) {
      case 0: W = qw1; break; case 1: W = qw2; break;
      case 2: W = kw1; break; case 3: W = kw2; break;
      case 4: W = vw1; break; case 5: W = vw2; break;
      default: W = xmw1; break;
    }
    u16* o = wsb + b * 16384;
    for (int i = 0; i < 128; ++i) {
      int idx = i * 128 + threadIdx.x;
      int h = idx >> 7, c = idx & 127;
      o[c * 128 + h] = f2bf(W[idx]);
    }
  } else {
    int r = b - 7;            // 0..127, rel = r-63
    int o = threadIdx.x;      // 0..127
    __shared__ float sc[128];
    float rel = (float)(r - 63);
    if (o < 64) {
      float f = expf((float)o * (-logf(10000.0f) / 63.0f));
      float a = rel * f;
      sc[o] = sinf(a);
      sc[o + 64] = cosf(a);
    }
    __syncthreads();
    float acc = t_b[o];
    for (int i = 0; i < 128; ++i) acc = fmaf(sc[i], t_w[i * 128 + o], acc);
    u16 bb = f2bf(acc);
    wsb[7 * 16384 + r * 128 + o] = bb;   // ErelB[r][h]
    wsb[8 * 16384 + o * 128 + r] = bb;   // ErelT[h][r]
  }
}

// D[m=o][n=t] = A(global [o][k], stride 128) x B(LDS swizzled [t][k]); out -> Ol[t][o] bf16
template <bool SILU, bool HASB, bool VT>
__device__ __forceinline__ void gemm128(const u16* __restrict__ Ag,
                                        const unsigned char* Bl,
                                        unsigned char* Ol,
                                        unsigned char* vTout,
                                        const float* __restrict__ bias,
                                        int w, int l) {
  const int lr = l & 15, lk = l >> 4;
  const int m0 = w * 16;
  float bj[4];
#pragma unroll
  for (int j = 0; j < 4; ++j) bj[j] = HASB ? bias[m0 + lk * 4 + j] : 0.f;
  f4v acc[4];
#pragma unroll
  for (int ni = 0; ni < 4; ++ni)
#pragma unroll
    for (int j = 0; j < 4; ++j) acc[ni][j] = bj[j];
#pragma unroll
  for (int kt = 0; kt < 4; ++kt) {
    s8v a = *(const s8v*)&Ag[(m0 + lr) * 128 + kt * 32 + lk * 8];
#pragma unroll
    for (int ni = 0; ni < 4; ++ni) {
      s8v b = *(const s8v*)(Bl + SW(ni * 16 + lr, kt * 64 + lk * 16));
      acc[ni] = MFMA16(a, b, acc[ni]);
    }
  }
#pragma unroll
  for (int ni = 0; ni < 4; ++ni) {
    int t = ni * 16 + lr;
    float v0 = acc[ni][0], v1 = acc[ni][1], v2 = acc[ni][2], v3 = acc[ni][3];
    if (SILU) {
      v0 *= __builtin_amdgcn_rcpf(1.0f + __expf(-v0));
      v1 *= __builtin_amdgcn_rcpf(1.0f + __expf(-v1));
      v2 *= __builtin_amdgcn_rcpf(1.0f + __expf(-v2));
      v3 *= __builtin_amdgcn_rcpf(1.0f + __expf(-v3));
    }
    unsigned int c0 = cvt2u(v0, v1), c1 = cvt2u(v2, v3);
    u32x2 st; st[0] = c0; st[1] = c1;
    *(u32x2*)(Ol + SW(t, m0 * 2 + lk * 8)) = st;
    if (VT) {
      *(u16*)(vTout + SWH(m0 + lk * 4 + 0, t * 2)) = (u16)(c0 & 0xffffu);
      *(u16*)(vTout + SWH(m0 + lk * 4 + 1, t * 2)) = (u16)(c0 >> 16);
      *(u16*)(vTout + SWH(m0 + lk * 4 + 2, t * 2)) = (u16)(c1 & 0xffffu);
      *(u16*)(vTout + SWH(m0 + lk * 4 + 3, t * 2)) = (u16)(c1 >> 16);
    }
  }
}

// LDS layout (bytes); total 81920 -> 2 blocks/CU
#define OFF_TOK 0        // tok [64]x256B  -> vT [128]x128B (SWH)
#define OFF_HID 16384    // hid [64]x256B  -> scoF f32 [64]x256B
#define OFF_Q   32768    // q   [64]x256B  -> A2 [64]x256B
#define OFF_K   49152    // k   [64]x256B  -> alpB [64]x128B + vxb(256B)@57344 + xls(768B)@57600
#define OFF_VX  57344
#define OFF_XLS 57600
#define OFF_V   65536    // v   [64]x256B  -> qE [64]x256B -> y [16]x128B
#define SMEM_SZ 81920

__launch_bounds__(512, 4)
__global__ void et_main(const float* __restrict__ xg, const float* __restrict__ hg,
                        const u16* __restrict__ wsb,
                        const float* __restrict__ qb1, const float* __restrict__ qb2,
                        const float* __restrict__ kb1, const float* __restrict__ kb2,
                        const float* __restrict__ vb1, const float* __restrict__ vb2,
                        const float* __restrict__ xmb1, const float* __restrict__ xmw2,
                        const float* __restrict__ xmb2,
                        float* __restrict__ xout, float* __restrict__ hout) {
  __shared__ __align__(16) unsigned char smem[SMEM_SZ];
  unsigned char* TOK = smem + OFF_TOK;
  unsigned char* HID = smem + OFF_HID;
  unsigned char* QB  = smem + OFF_Q;
  unsigned char* KB  = smem + OFF_K;
  unsigned char* VB  = smem + OFF_V;
  unsigned char* VT  = TOK;
  unsigned char* SCO = HID;
  unsigned char* A2  = QB;
  unsigned char* ALP = KB;
  unsigned char* Y   = VB;     // y [16][64] u16, plain 128B rows
  float* vxb = (float*)(smem + OFF_VX);
  float* xls = (float*)(smem + OFF_XLS);

  const u16* WTq1 = wsb + 0 * 16384;
  const u16* WTq2 = wsb + 1 * 16384;
  const u16* WTk1 = wsb + 2 * 16384;
  const u16* WTk2 = wsb + 3 * 16384;
  const u16* WTv1 = wsb + 4 * 16384;
  const u16* WTv2 = wsb + 5 * 16384;
  const u16* WTxm = wsb + 6 * 16384;
  const u16* ErelB = wsb + 7 * 16384;
  const u16* ErelT = wsb + 8 * 16384;

  const int tid = threadIdx.x;
  const int l = tid & 63;
  const int w = __builtin_amdgcn_readfirstlane(tid >> 6);
  const int n = blockIdx.x;
  const size_t hbase = (size_t)n * 8192;

  // ---- tok load: 16 coalesced dword loads -> 8 cvt_pk -> 2 b128 LDS writes ----
  {
    int t = tid & 63;
    int c0 = (tid >> 6) * 2;
#pragma unroll
    for (int cc = 0; cc < 2; ++cc) {
      int c = c0 + cc;
      float hv[8];
#pragma unroll
      for (int j = 0; j < 8; ++j) hv[j] = hg[hbase + (size_t)(c * 8 + j) * 64 + t];
      u32x4 pk;
#pragma unroll
      for (int j = 0; j < 4; ++j) pk[j] = cvt2u(hv[2 * j], hv[2 * j + 1]);
      *(u32x4*)(TOK + SW(t, c * 16)) = pk;
    }
  }
  __syncthreads();

  // ---- MLPs ----
  gemm128<true , true, false>(WTq1, TOK, HID, nullptr, qb1, w, l); __syncthreads();
  gemm128<false, true, false>(WTq2, HID, QB , nullptr, qb2, w, l); __syncthreads();
  gemm128<true , true, false>(WTk1, TOK, HID, nullptr, kb1, w, l); __syncthreads();
  gemm128<false, true, false>(WTk2, HID, KB , nullptr, kb2, w, l); __syncthreads();
  gemm128<true , true, false>(WTv1, TOK, HID, nullptr, vb1, w, l); __syncthreads();
  gemm128<false, true, true >(WTv2, HID, VB , VT     , vb2, w, l); __syncthreads();
  gemm128<true , true, false>(WTxm, VB , HID, nullptr, xmb1, w, l); __syncthreads();

  // ---- vx partial (register) + qE GEMM ----
  float vxreg;
  {
    int t = tid >> 3, g = tid & 7;
    s8v h0 = *(const s8v*)(HID + SW(t, g * 32));
    s8v h1 = *(const s8v*)(HID + SW(t, g * 32 + 16));
    float sum = 0.f;
#pragma unroll
    for (int c = 0; c < 8; ++c) sum = fmaf(bf2f((u16)h0[c]), xmw2[g * 16 + c], sum);
#pragma unroll
    for (int c = 0; c < 8; ++c) sum = fmaf(bf2f((u16)h1[c]), xmw2[g * 16 + 8 + c], sum);
    sum += __shfl_xor(sum, 1, 64);
    sum += __shfl_xor(sum, 2, 64);
    sum += __shfl_xor(sum, 4, 64);
    vxreg = sum;
  }
  gemm128<false, false, false>(ErelB, QB, VB, nullptr, nullptr, w, l);   // qE[t][r]
  __syncthreads();

  // ---- scores[t][s] = q.k + qE[t][t-s+63] -> scoF f32 ----
  {
    const int lr = l & 15, lk = l >> 4;
    const int m0 = (w & 3) * 16;     // s tile
    const int n0 = (w >> 2) * 32;    // t tiles
    f4v acc[2];
#pragma unroll
    for (int ni = 0; ni < 2; ++ni)
#pragma unroll
      for (int j = 0; j < 4; ++j) acc[ni][j] = 0.f;
#pragma unroll
    for (int kt = 0; kt < 4; ++kt) {
      s8v a = *(const s8v*)(KB + SW(m0 + lr, kt * 64 + lk * 16));
#pragma unroll
      for (int ni = 0; ni < 2; ++ni) {
        s8v b = *(const s8v*)(QB + SW(n0 + ni * 16 + lr, kt * 64 + lk * 16));
        acc[ni] = MFMA16(a, b, acc[ni]);
      }
    }
#pragma unroll
    for (int ni = 0; ni < 2; ++ni) {
      int t = n0 + ni * 16 + lr;
      float4 out;
      float* op = (float*)&out;
#pragma unroll
      for (int j = 0; j < 4; ++j) {
        int s = m0 + lk * 4 + j;
        int r = t - s + 63;
        op[j] = acc[ni][j] + bf2f(*(const u16*)(VB + SW(t, r * 2)));
      }
      *(float4*)(SCO + SW(t, m0 * 4 + lk * 16)) = out;
    }
  }
  __syncthreads();

  // ---- phase1: softmax + ALP store + zero A2/y + vxb/xls stores ----
  unsigned int ac[4];
  {
    int t = tid >> 3, g = tid & 7;
    float4 v0 = *(float4*)(SCO + SW(t, g * 32));
    float4 v1 = *(float4*)(SCO + SW(t, g * 32 + 16));
    float e[8] = {v0.x, v0.y, v0.z, v0.w, v1.x, v1.y, v1.z, v1.w};
    float m = e[0];
#pragma unroll
    for (int i = 1; i < 8; ++i) m = fmaxf(m, e[i]);
    m = fmaxf(m, __shfl_xor(m, 1, 64));
    m = fmaxf(m, __shfl_xor(m, 2, 64));
    m = fmaxf(m, __shfl_xor(m, 4, 64));
    float s = 0.f;
#pragma unroll
    for (int i = 0; i < 8; ++i) { e[i] = __expf(e[i] - m); s += e[i]; }
    s += __shfl_xor(s, 1, 64);
    s += __shfl_xor(s, 2, 64);
    s += __shfl_xor(s, 4, 64);
    float inv = __builtin_amdgcn_rcpf(s);
#pragma unroll
    for (int i = 0; i < 4; ++i) ac[i] = cvt2u(e[2 * i] * inv, e[2 * i + 1] * inv);
    u32x4 st; st[0] = ac[0]; st[1] = ac[1]; st[2] = ac[2]; st[3] = ac[3];
    *(u32x4*)(ALP + SWH(t, g * 16)) = st;
    // zero A2 tile (16 KB) and y rows 4..15
    u32x4 zz; zz[0] = zz[1] = zz[2] = zz[3] = 0;
    *(u32x4*)(A2 + tid * 16) = zz;
    *(u32x4*)(A2 + 8192 + tid * 16) = zz;
    if (tid < 96) *(u32x4*)(Y + 512 + tid * 16) = zz;
    if ((tid & 7) == 0) vxb[t] = vxreg + xmb2[0];
    if (tid < 192) xls[tid] = xg[n * 192 + tid];
  }
  __syncthreads();

  // ---- phase2: A2 band scatter from registers + y build ----
  {
    int t = tid >> 3, g = tid & 7;
    u16 ab[8];
#pragma unroll
    for (int i = 0; i < 4; ++i) { ab[2 * i] = (u16)(ac[i] & 0xffffu); ab[2 * i + 1] = (u16)(ac[i] >> 16); }
#pragma unroll
    for (int i = 0; i < 8; ++i) {
      int r = t + 63 - 8 * g - i;              // always in [0,127]
      *(u16*)(A2 + SW(t, r * 2)) = ab[i];
    }
    if (tid >= 64 && tid < 128) {
      int s2 = tid - 64;
      float vv = vxb[s2];
      unsigned int p0 = cvt2u(vv, vv * xls[s2]);
      unsigned int p1 = cvt2u(vv * xls[64 + s2], vv * xls[128 + s2]);
      *(u16*)(Y + 0 * 128 + 2 * s2) = (u16)(p0 & 0xffffu);
      *(u16*)(Y + 1 * 128 + 2 * s2) = (u16)(p0 >> 16);
      *(u16*)(Y + 2 * 128 + 2 * s2) = (u16)(p1 & 0xffffu);
      *(u16*)(Y + 3 * 128 + 2 * s2) = (u16)(p1 >> 16);
    }
  }
  __syncthreads();

  // ---- dh = alpha@v + A2@Erel ; h_out = h + dh ; wave0: x mini-GEMM ----
  {
    const int lr = l & 15, lk = l >> 4;
    const int m0 = w * 16;
    float hld[16];
#pragma unroll
    for (int ni = 0; ni < 4; ++ni) {
      size_t base = hbase + (size_t)(m0 + lk * 4) * 64 + ni * 16 + lr;
#pragma unroll
      for (int j = 0; j < 4; ++j) hld[ni * 4 + j] = hg[base + j * 64];
    }
    f4v acc[4];
#pragma unroll
    for (int ni = 0; ni < 4; ++ni)
#pragma unroll
      for (int j = 0; j < 4; ++j) acc[ni][j] = 0.f;
#pragma unroll
    for (int kt = 0; kt < 2; ++kt) {
      s8v a = *(const s8v*)(VT + SWH(m0 + lr, kt * 64 + lk * 16));
#pragma unroll
      for (int ni = 0; ni < 4; ++ni) {
        s8v b = *(const s8v*)(ALP + SWH(ni * 16 + lr, kt * 64 + lk * 16));
        acc[ni] = MFMA16(a, b, acc[ni]);
      }
    }
#pragma unroll
    for (int kt = 0; kt < 4; ++kt) {
      s8v a = *(const s8v*)&ErelT[(m0 + lr) * 128 + kt * 32 + lk * 8];
#pragma unroll
      for (int ni = 0; ni < 4; ++ni) {
        s8v b = *(const s8v*)(A2 + SW(ni * 16 + lr, kt * 64 + lk * 16));
        acc[ni] = MFMA16(a, b, acc[ni]);
      }
    }
#pragma unroll
    for (int ni = 0; ni < 4; ++ni) {
      size_t base = hbase + (size_t)(m0 + lk * 4) * 64 + ni * 16 + lr;
#pragma unroll
      for (int j = 0; j < 4; ++j) hout[base + j * 64] = hld[ni * 4 + j] + acc[ni][j];
    }

    if (w == 0) {   // x update: [a1;a2] = y @ alpha^T via MFMA
      f4v xa[4];
#pragma unroll
      for (int ni = 0; ni < 4; ++ni)
#pragma unroll
        for (int j = 0; j < 4; ++j) xa[ni][j] = 0.f;
#pragma unroll
      for (int kt = 0; kt < 2; ++kt) {
        s8v a = *(const s8v*)(Y + lr * 128 + kt * 64 + lk * 16);
#pragma unroll
        for (int ni = 0; ni < 4; ++ni) {
          s8v b = *(const s8v*)(ALP + SWH(ni * 16 + lr, kt * 64 + lk * 16));
          xa[ni] = MFMA16(a, b, xa[ni]);
        }
      }
      if (lk == 0) {
#pragma unroll
        for (int ni = 0; ni < 4; ++ni) {
          int t = ni * 16 + lr;
          float a1 = xa[ni][0];
#pragma unroll
          for (int d = 0; d < 3; ++d) {
            float xv = xls[d * 64 + t];
            xout[n * 192 + d * 64 + t] = fmaf(xv, a1, xv) - xa[ni][1 + d];
          }
        }
      }
    }
  }
}

extern "C" void kernel_launch(void* const* d_in, const int* in_sizes, int n_in,
                              void* d_out, int out_size, void* d_ws, size_t ws_size,
                              hipStream_t stream) {
  const float* xg   = (const float*)d_in[0];
  const float* hg   = (const float*)d_in[1];
  const float* qw1  = (const float*)d_in[2];
  const float* qb1  = (const float*)d_in[3];
  const float* qw2  = (const float*)d_in[4];
  const float* qb2  = (const float*)d_in[5];
  const float* kw1  = (const float*)d_in[6];
  const float* kb1  = (const float*)d_in[7];
  const float* kw2  = (const float*)d_in[8];
  const float* kb2  = (const float*)d_in[9];
  const float* vw1  = (const float*)d_in[10];
  const float* vb1  = (const float*)d_in[11];
  const float* vw2  = (const float*)d_in[12];
  const float* vb2  = (const float*)d_in[13];
  const float* xmw1 = (const float*)d_in[14];
  const float* xmb1 = (const float*)d_in[15];
  const float* xmw2 = (const float*)d_in[16];
  const float* xmb2 = (const float*)d_in[17];
  const float* t_w  = (const float*)d_in[18];
  const float* t_b  = (const float*)d_in[19];

  u16* wsb = (u16*)d_ws;   // 9 * 16384 u16 = 294912 B
  float* xout = (float*)d_out;
  float* hout = xout + (size_t)NN * 192;

  prep_kernel<<<135, 128, 0, stream>>>(qw1, qw2, kw1, kw2, vw1, vw2, xmw1, t_w, t_b, wsb);
  et_main<<<NN, 512, 0, stream>>>(xg, hg, wsb,
                                  qb1, qb2, kb1, kb2, vb1, vb2, xmb1, xmw2, xmb2,
                                  xout, hout);
}

// Round 5
// 174.561 us; speedup vs baseline: 27.7746x; 1.1949x over previous
//
#include <hip/hip_runtime.h>
#include <hip/hip_bf16.h>
#include <math.h>

#define NN 4096

typedef __attribute__((ext_vector_type(8))) short s8v;        // 8 bf16 = 16B
typedef __attribute__((ext_vector_type(4))) float f4v;        // MFMA accum
typedef __attribute__((ext_vector_type(4))) unsigned int u32x4;
typedef __attribute__((ext_vector_type(2))) unsigned int u32x2;
typedef unsigned short u16;

static __device__ __forceinline__ f4v MFMA16(s8v a, s8v b, f4v c) {
  return __builtin_amdgcn_mfma_f32_16x16x32_bf16(a, b, c, 0, 0, 0);
}
static __device__ __forceinline__ u16 f2bf(float f) {
  union { float f; unsigned int u; } v; v.f = f;
  unsigned int r = v.u + 0x7fffu + ((v.u >> 16) & 1u);
  return (u16)(r >> 16);
}
static __device__ __forceinline__ float bf2f(u16 u) {
  union { unsigned int u; float f; } v; v.u = ((unsigned int)u) << 16;
  return v.f;
}
static __device__ __forceinline__ unsigned int cvt2u(float lo, float hi) {
  __hip_bfloat162 h = __float22bfloat162_rn(make_float2(lo, hi));
  union { __hip_bfloat162 b; unsigned int u; } c; c.b = h; return c.u;
}

// swizzled byte offsets: 256B rows and 128B rows
#define SW(row, byte)  ((row) * 256 + ((byte) ^ (((row) & 7) << 4)))
#define SWH(row, byte) ((row) * 128 + ((byte) ^ (((row) & 7) << 4)))

// ws regions (u16 offsets). Fragment layout: base + ((mt*4 + kt)*64 + lane)*8 + j
#define FA_OFF 0         // [q1;k1;v1]   24 tiles
#define FB_OFF 49152     // [q2;k2;v2]   24 tiles
#define FC_OFF 98304     // [xm1 (0-7); ErelB (8-15)] 16 tiles
#define FD_OFF 131072    // ErelT        8 tiles
// total 147456 u16 = 294912 B

// ---------------- prep: fragment all weights + Erel (both layouts) ----------------
__global__ void prep_kernel(const float* __restrict__ qw1, const float* __restrict__ kw1,
                            const float* __restrict__ vw1, const float* __restrict__ qw2,
                            const float* __restrict__ kw2, const float* __restrict__ vw2,
                            const float* __restrict__ xmw1,
                            const float* __restrict__ t_w, const float* __restrict__ t_b,
                            u16* __restrict__ wsb) {
  const int b = blockIdx.x, tid = threadIdx.x;
  const int kt = tid >> 6, l = tid & 63, lr = l & 15, lk = l >> 4;
  if (b < 56) {
    const float* W; int mt; u16* base;
    if (b < 24)      { base = wsb + FA_OFF; mt = b;      W = (b < 8) ? qw1 : (b < 16) ? kw1 : vw1; }
    else if (b < 48) { base = wsb + FB_OFF; mt = b - 24; W = (mt < 8) ? qw2 : (mt < 16) ? kw2 : vw2; }
    else             { base = wsb + FC_OFF; mt = b - 48; W = xmw1; }
    const int ch = (mt & 7) * 16;
    u16 o[8];
#pragma unroll
    for (int j = 0; j < 8; ++j) o[j] = f2bf(W[(kt * 32 + lk * 8 + j) * 128 + ch + lr]);
    u32x4 pk;
#pragma unroll
    for (int i = 0; i < 4; ++i) pk[i] = (unsigned int)o[2 * i] | ((unsigned int)o[2 * i + 1] << 16);
    *(u32x4*)&base[((mt * 4 + kt) * 64 + l) * 8] = pk;
  } else {
    // ErelB tiles (rows r = rt*16+lr, cols h = kt*32+lk*8+j) + dual-write transposed frags (FD)
    const int rt = b - 56;
    const int r = rt * 16 + lr;
    const float rel = (float)(r - 63);
    const int h0 = kt * 32 + lk * 8;
    float acc[8];
#pragma unroll
    for (int j = 0; j < 8; ++j) acc[j] = t_b[h0 + j];
    const float C = -logf(10000.0f) / 63.0f;
    for (int i = 0; i < 64; ++i) {
      float f = expf((float)i * C);
      float a = rel * f;
      float sn = sinf(a), cs = cosf(a);
#pragma unroll
      for (int j = 0; j < 8; ++j) acc[j] = fmaf(sn, t_w[i * 128 + h0 + j], acc[j]);
#pragma unroll
      for (int j = 0; j < 8; ++j) acc[j] = fmaf(cs, t_w[(i + 64) * 128 + h0 + j], acc[j]);
    }
    u16 o[8];
#pragma unroll
    for (int j = 0; j < 8; ++j) o[j] = f2bf(acc[j]);
    u32x4 pk;
#pragma unroll
    for (int i = 0; i < 4; ++i) pk[i] = (unsigned int)o[2 * i] | ((unsigned int)o[2 * i + 1] << 16);
    *(u32x4*)&wsb[FC_OFF + (((8 + rt) * 4 + kt) * 64 + l) * 8] = pk;
    // FD: value E[r][h0+j] -> tile ct=h0>>4, lane row (h0&15)+j, k-index r
    const int ct = h0 >> 4, lrp = h0 & 15;
    const int ktp = r >> 5, lkp = (r >> 3) & 3, jp = r & 7;
#pragma unroll
    for (int j = 0; j < 8; ++j)
      wsb[FD_OFF + ((ct * 4 + ktp) * 64 + lkp * 16 + lrp + j) * 8 + jp] = o[j];
  }
}

// one 16ch x 64t tile: A = pre-fragmented global, B = LDS SW; out bf16 -> Ol[t][ocol]
template <bool SILU, bool HASB>
__device__ __forceinline__ void tile_gemm(const u16* __restrict__ fr,
                                          const unsigned char* Bl, unsigned char* Ol,
                                          const float* __restrict__ bias,
                                          int ocol, int l) {
  const int lr = l & 15, lk = l >> 4;
  s8v a[4];
#pragma unroll
  for (int kt = 0; kt < 4; ++kt) a[kt] = *(const s8v*)&fr[(kt * 64 + l) * 8];
  float bj[4];
#pragma unroll
  for (int j = 0; j < 4; ++j) bj[j] = HASB ? bias[lk * 4 + j] : 0.f;
  f4v acc[4];
#pragma unroll
  for (int ni = 0; ni < 4; ++ni)
#pragma unroll
    for (int j = 0; j < 4; ++j) acc[ni][j] = bj[j];
#pragma unroll
  for (int kt = 0; kt < 4; ++kt)
#pragma unroll
    for (int ni = 0; ni < 4; ++ni)
      acc[ni] = MFMA16(a[kt], *(const s8v*)(Bl + SW(ni * 16 + lr, kt * 64 + lk * 16)), acc[ni]);
#pragma unroll
  for (int ni = 0; ni < 4; ++ni) {
    int t = ni * 16 + lr;
    float v0 = acc[ni][0], v1 = acc[ni][1], v2 = acc[ni][2], v3 = acc[ni][3];
    if (SILU) {
      v0 *= __builtin_amdgcn_rcpf(1.0f + __expf(-v0));
      v1 *= __builtin_amdgcn_rcpf(1.0f + __expf(-v1));
      v2 *= __builtin_amdgcn_rcpf(1.0f + __expf(-v2));
      v3 *= __builtin_amdgcn_rcpf(1.0f + __expf(-v3));
    }
    u32x2 st; st[0] = cvt2u(v0, v1); st[1] = cvt2u(v2, v3);
    *(u32x2*)(Ol + SW(t, ocol + lk * 8)) = st;
  }
}

// LDS: 5 slots x 16KB = 80KB -> 2 blocks/CU
// S0: TOK -> K -> {ALP(8K) | Y(2K)@8192 | VXP(2K)@10240 | XLS@12288}
// S1: HQ -> V          S2: HK -> qE -> vT          S3: HV -> SCO          S4: Q -> A2
__launch_bounds__(512, 4)
__global__ void et_main(const float* __restrict__ xg, const float* __restrict__ hg,
                        const u16* __restrict__ wsb,
                        const float* __restrict__ qb1, const float* __restrict__ qb2,
                        const float* __restrict__ kb1, const float* __restrict__ kb2,
                        const float* __restrict__ vb1, const float* __restrict__ vb2,
                        const float* __restrict__ xmb1, const float* __restrict__ xmw2,
                        const float* __restrict__ xmb2,
                        float* __restrict__ xout, float* __restrict__ hout) {
  __shared__ __align__(16) unsigned char smem[81920];
  unsigned char* S0 = smem;
  unsigned char* S1 = smem + 16384;
  unsigned char* S2 = smem + 32768;
  unsigned char* S3 = smem + 49152;
  unsigned char* S4 = smem + 65536;
  unsigned char* ALP = S0;
  unsigned char* YB  = S0 + 8192;
  float* VXP = (float*)(S0 + 10240);
  float* XLS = (float*)(S0 + 12288);

  const u16* FA = wsb + FA_OFF;
  const u16* FB = wsb + FB_OFF;
  const u16* FC = wsb + FC_OFF;
  const u16* FD = wsb + FD_OFF;

  const int tid = threadIdx.x;
  const int l = tid & 63;
  const int lr = l & 15, lk = l >> 4;
  const int w = __builtin_amdgcn_readfirstlane(tid >> 6);
  const int n = blockIdx.x;
  const size_t hbase = (size_t)n * 8192;

  // ---- P0: tok -> S0 ----
  {
    int t = tid & 63, c0 = (tid >> 6) * 2;
#pragma unroll
    for (int cc = 0; cc < 2; ++cc) {
      int c = c0 + cc;
      float hv[8];
#pragma unroll
      for (int j = 0; j < 8; ++j) hv[j] = hg[hbase + (size_t)(c * 8 + j) * 64 + t];
      u32x4 pk;
#pragma unroll
      for (int j = 0; j < 4; ++j) pk[j] = cvt2u(hv[2 * j], hv[2 * j + 1]);
      *(u32x4*)(S0 + SW(t, c * 16)) = pk;
    }
  }
  __syncthreads();

  // ---- P1: fused [q1;k1;v1] @ tok -> HQ(S1), HK(S2), HV(S3) ----
  tile_gemm<true, true>(FA + (w)      * 2048, S0, S1, qb1 + w * 16, w * 32, l);
  tile_gemm<true, true>(FA + (w + 8)  * 2048, S0, S2, kb1 + w * 16, w * 32, l);
  tile_gemm<true, true>(FA + (w + 16) * 2048, S0, S3, vb1 + w * 16, w * 32, l);
  __syncthreads();

  // ---- P2: q2 (HQ->Q:S4), k2 (HK->K:S0) ----
  tile_gemm<false, true>(FB + (w)     * 2048, S1, S4, qb2 + w * 16, w * 32, l);
  tile_gemm<false, true>(FB + (w + 8) * 2048, S2, S0, kb2 + w * 16, w * 32, l);
  __syncthreads();

  // ---- P3: v2 (HV->V:S1), qE = ErelB @ q (Q->S2) ----
  tile_gemm<false, true >(FB + (w + 16) * 2048, S3, S1, vb2 + w * 16, w * 32, l);
  tile_gemm<false, false>(FC + (w + 8)  * 2048, S4, S2, nullptr,      w * 32, l);
  __syncthreads();

  // ---- P4: xm GEMM (vx in regs) + scores -> SCO(S3) ----
  float vxr[4];
  {
    const u16* fx = FC + w * 2048;
    s8v a[4];
#pragma unroll
    for (int kt = 0; kt < 4; ++kt) a[kt] = *(const s8v*)&fx[(kt * 64 + l) * 8];
    float bj[4], w2[4];
#pragma unroll
    for (int j = 0; j < 4; ++j) { bj[j] = xmb1[w * 16 + lk * 4 + j]; w2[j] = xmw2[w * 16 + lk * 4 + j]; }
    f4v acc[4];
#pragma unroll
    for (int ni = 0; ni < 4; ++ni)
#pragma unroll
      for (int j = 0; j < 4; ++j) acc[ni][j] = bj[j];
#pragma unroll
    for (int kt = 0; kt < 4; ++kt)
#pragma unroll
      for (int ni = 0; ni < 4; ++ni)
        acc[ni] = MFMA16(a[kt], *(const s8v*)(S1 + SW(ni * 16 + lr, kt * 64 + lk * 16)), acc[ni]);
#pragma unroll
    for (int ni = 0; ni < 4; ++ni) {
      float s = 0.f;
#pragma unroll
      for (int j = 0; j < 4; ++j) {
        float v = acc[ni][j];
        v *= __builtin_amdgcn_rcpf(1.0f + __expf(-v));
        s = fmaf(v, w2[j], s);
      }
      s += __shfl_xor(s, 16, 64);
      s += __shfl_xor(s, 32, 64);
      vxr[ni] = s;
    }
  }
  {
    const int m0 = (w & 3) * 16, n0 = (w >> 2) * 32;
    f4v acc[2];
#pragma unroll
    for (int ni = 0; ni < 2; ++ni)
#pragma unroll
      for (int j = 0; j < 4; ++j) acc[ni][j] = 0.f;
#pragma unroll
    for (int kt = 0; kt < 4; ++kt) {
      s8v a = *(const s8v*)(S0 + SW(m0 + lr, kt * 64 + lk * 16));
#pragma unroll
      for (int ni = 0; ni < 2; ++ni)
        acc[ni] = MFMA16(a, *(const s8v*)(S4 + SW(n0 + ni * 16 + lr, kt * 64 + lk * 16)), acc[ni]);
    }
#pragma unroll
    for (int ni = 0; ni < 2; ++ni) {
      int t = n0 + ni * 16 + lr;
      float4 out;
      float* op = (float*)&out;
#pragma unroll
      for (int j = 0; j < 4; ++j) {
        int s = m0 + lk * 4 + j;
        op[j] = acc[ni][j] + bf2f(*(const u16*)(S2 + SW(t, (t - s + 63) * 2)));
      }
      *(float4*)(S3 + SW(t, m0 * 4 + lk * 16)) = out;
    }
  }
  __syncthreads();

  // ---- P5a: softmax -> ALP + regs; zero A2/Y; store vxp; load xls ----
  unsigned int ac[4];
  {
    int t = tid >> 3, g = tid & 7;
    float4 v0 = *(float4*)(S3 + SW(t, g * 32));
    float4 v1 = *(float4*)(S3 + SW(t, g * 32 + 16));
    float e[8] = {v0.x, v0.y, v0.z, v0.w, v1.x, v1.y, v1.z, v1.w};
    float m = e[0];
#pragma unroll
    for (int i = 1; i < 8; ++i) m = fmaxf(m, e[i]);
    m = fmaxf(m, __shfl_xor(m, 1, 64));
    m = fmaxf(m, __shfl_xor(m, 2, 64));
    m = fmaxf(m, __shfl_xor(m, 4, 64));
    float s = 0.f;
#pragma unroll
    for (int i = 0; i < 8; ++i) { e[i] = __expf(e[i] - m); s += e[i]; }
    s += __shfl_xor(s, 1, 64);
    s += __shfl_xor(s, 2, 64);
    s += __shfl_xor(s, 4, 64);
    float inv = __builtin_amdgcn_rcpf(s);
#pragma unroll
    for (int i = 0; i < 4; ++i) ac[i] = cvt2u(e[2 * i] * inv, e[2 * i + 1] * inv);
    u32x4 st; st[0] = ac[0]; st[1] = ac[1]; st[2] = ac[2]; st[3] = ac[3];
    *(u32x4*)(ALP + SWH(t, g * 16)) = st;
    u32x4 zz; zz[0] = zz[1] = zz[2] = zz[3] = 0;
    *(u32x4*)(S4 + tid * 16) = zz;
    *(u32x4*)(S4 + 8192 + tid * 16) = zz;
    if (tid < 96) *(u32x4*)(YB + 512 + tid * 16) = zz;
    if (l < 16) {
#pragma unroll
      for (int ni = 0; ni < 4; ++ni) VXP[w * 64 + ni * 16 + l] = vxr[ni];
    }
    if (tid < 192) XLS[tid] = xg[n * 192 + tid];
  }
  __syncthreads();

  // ---- P5b: A2 band scatter; V transpose S1->vT(S2); vx reduce + Y rows 0-3 ----
  {
    int t = tid >> 3, g = tid & 7;
    u16 ab[8];
#pragma unroll
    for (int i = 0; i < 4; ++i) { ab[2 * i] = (u16)(ac[i] & 0xffffu); ab[2 * i + 1] = (u16)(ac[i] >> 16); }
#pragma unroll
    for (int i = 0; i < 8; ++i)
      *(u16*)(S4 + SW(t, (t + 63 - 8 * g - i) * 2)) = ab[i];
  }
  {
    int c = ((w & 1) << 6) + l;      // 0..127
    int t0 = (w >> 1) << 4;          // 0,16,32,48
    u16 vt[16];
#pragma unroll
    for (int i = 0; i < 16; ++i) vt[i] = *(const u16*)(S1 + SW(t0 + i, c * 2));
    u32x4 p0, p1;
#pragma unroll
    for (int i = 0; i < 4; ++i) {
      p0[i] = (unsigned int)vt[2 * i]     | ((unsigned int)vt[2 * i + 1] << 16);
      p1[i] = (unsigned int)vt[8 + 2 * i] | ((unsigned int)vt[9 + 2 * i] << 16);
    }
    *(u32x4*)(S2 + SWH(c, t0 * 2))      = p0;
    *(u32x4*)(S2 + SWH(c, t0 * 2 + 16)) = p1;
  }
  if (tid < 64) {
    float s = VXP[tid];
#pragma unroll
    for (int wv = 1; wv < 8; ++wv) s += VXP[wv * 64 + tid];
    s += xmb2[0];
    unsigned int p0 = cvt2u(s, s * XLS[tid]);
    unsigned int p1 = cvt2u(s * XLS[64 + tid], s * XLS[128 + tid]);
    *(u16*)(YB + SWH(0, 2 * tid)) = (u16)(p0 & 0xffffu);
    *(u16*)(YB + SWH(1, 2 * tid)) = (u16)(p0 >> 16);
    *(u16*)(YB + SWH(2, 2 * tid)) = (u16)(p1 & 0xffffu);
    *(u16*)(YB + SWH(3, 2 * tid)) = (u16)(p1 >> 16);
  }
  __syncthreads();

  // ---- P6: dh = alpha@v + A2@Erel ; h_out = h + dh ; waves 0-3: x update ----
  {
    const int m0 = w * 16;
    float hld[16];
#pragma unroll
    for (int ni = 0; ni < 4; ++ni) {
      size_t base = hbase + (size_t)(m0 + lk * 4) * 64 + ni * 16 + lr;
#pragma unroll
      for (int j = 0; j < 4; ++j) hld[ni * 4 + j] = hg[base + j * 64];
    }
    f4v acc[4];
#pragma unroll
    for (int ni = 0; ni < 4; ++ni)
#pragma unroll
      for (int j = 0; j < 4; ++j) acc[ni][j] = 0.f;
#pragma unroll
    for (int kt = 0; kt < 2; ++kt) {
      s8v a = *(const s8v*)(S2 + SWH(m0 + lr, kt * 64 + lk * 16));
#pragma unroll
      for (int ni = 0; ni < 4; ++ni)
        acc[ni] = MFMA16(a, *(const s8v*)(ALP + SWH(ni * 16 + lr, kt * 64 + lk * 16)), acc[ni]);
    }
    const u16* fd = FD + w * 2048;
#pragma unroll
    for (int kt = 0; kt < 4; ++kt) {
      s8v a = *(const s8v*)&fd[(kt * 64 + l) * 8];
#pragma unroll
      for (int ni = 0; ni < 4; ++ni)
        acc[ni] = MFMA16(a, *(const s8v*)(S4 + SW(ni * 16 + lr, kt * 64 + lk * 16)), acc[ni]);
    }
#pragma unroll
    for (int ni = 0; ni < 4; ++ni) {
      size_t base = hbase + (size_t)(m0 + lk * 4) * 64 + ni * 16 + lr;
#pragma unroll
      for (int j = 0; j < 4; ++j) hout[base + j * 64] = hld[ni * 4 + j] + acc[ni][j];
    }
    if (w < 4) {
      f4v xa;
#pragma unroll
      for (int j = 0; j < 4; ++j) xa[j] = 0.f;
#pragma unroll
      for (int kt = 0; kt < 2; ++kt)
        xa = MFMA16(*(const s8v*)(YB + SWH(lr, kt * 64 + lk * 16)),
                    *(const s8v*)(ALP + SWH(w * 16 + lr, kt * 64 + lk * 16)), xa);
      if (lk == 0) {
        int t = w * 16 + lr;
        float a1 = xa[0];
#pragma unroll
        for (int d = 0; d < 3; ++d) {
          float xv = XLS[d * 64 + t];
          xout[n * 192 + d * 64 + t] = fmaf(xv, a1, xv) - xa[1 + d];
        }
      }
    }
  }
}

extern "C" void kernel_launch(void* const* d_in, const int* in_sizes, int n_in,
                              void* d_out, int out_size, void* d_ws, size_t ws_size,
                              hipStream_t stream) {
  const float* xg   = (const float*)d_in[0];
  const float* hg   = (const float*)d_in[1];
  const float* qw1  = (const float*)d_in[2];
  const float* qb1  = (const float*)d_in[3];
  const float* qw2  = (const float*)d_in[4];
  const float* qb2  = (const float*)d_in[5];
  const float* kw1  = (const float*)d_in[6];
  const float* kb1  = (const float*)d_in[7];
  const float* kw2  = (const float*)d_in[8];
  const float* kb2  = (const float*)d_in[9];
  const float* vw1  = (const float*)d_in[10];
  const float* vb1  = (const float*)d_in[11];
  const float* vw2  = (const float*)d_in[12];
  const float* vb2  = (const float*)d_in[13];
  const float* xmw1 = (const float*)d_in[14];
  const float* xmb1 = (const float*)d_in[15];
  const float* xmw2 = (const float*)d_in[16];
  const float* xmb2 = (const float*)d_in[17];
  const float* t_w  = (const float*)d_in[18];
  const float* t_b  = (const float*)d_in[19];

  u16* wsb = (u16*)d_ws;   // 294912 B
  float* xout = (float*)d_out;
  float* hout = xout + (size_t)NN * 192;

  prep_kernel<<<64, 256, 0, stream>>>(qw1, kw1, vw1, qw2, kw2, vw2, xmw1, t_w, t_b, wsb);
  et_main<<<NN, 512, 0, stream>>>(xg, hg, wsb,
                                  qb1, qb2, kb1, kb2, vb1, vb2, xmb1, xmw2, xmb2,
                                  xout, hout);
}